// Round 5
// baseline (451.591 us; speedup 1.0000x reference)
//
#include <hip/hip_runtime.h>
#include <hip/hip_bf16.h>

#define NROWS 100000
#define NH 8
#define RPC 1568     // k1 rows per chunk (64 chunks)
#define NSUB 49      // 32-row subtiles per chunk
#define NCH 64       // number of k1 chunks

typedef short s16x8 __attribute__((ext_vector_type(8)));
typedef float f32x4 __attribute__((ext_vector_type(4)));
typedef unsigned short u16;

__device__ __forceinline__ u16 f2bf(float f) {
  union { float f; unsigned u; } x; x.f = f;
  unsigned r = (x.u + 0x7FFFu + ((x.u >> 16) & 1u)) >> 16;
  return (u16)r;
}
__device__ __forceinline__ float bf2f(u16 b) {
  union { unsigned u; float f; } x; x.u = ((unsigned)b) << 16;
  return x.f;
}

// ---------------------------------------------------------------------------
// k_cvt: x fp32 -> bf16 (row-major [N][256]); removes all conversion VALU
// from the GEMM kernels and halves their read traffic.
// ---------------------------------------------------------------------------
__global__ __launch_bounds__(256) void k_cvt(
    const float* __restrict__ x, u16* __restrict__ xb)
{
  size_t idx = (size_t)(blockIdx.x * 256 + threadIdx.x) * 8;
  if (idx >= (size_t)NROWS * 256) return;
  float4 f0 = *(const float4*)(x + idx);
  float4 f1 = *(const float4*)(x + idx + 4);
  *(ushort4*)(xb + idx)     = make_ushort4(f2bf(f0.x), f2bf(f0.y), f2bf(f0.z), f2bf(f0.w));
  *(ushort4*)(xb + idx + 4) = make_ushort4(f2bf(f1.x), f2bf(f1.y), f2bf(f1.z), f2bf(f1.w));
}

// ---------------------------------------------------------------------------
// k0: pack W to bf16 MFMA A-fragments (layout identical to round 4).
// ---------------------------------------------------------------------------
__global__ __launch_bounds__(256) void k0_pack(
    const float* __restrict__ Wq, const float* __restrict__ Wk,
    const float* __restrict__ Wv, u16* __restrict__ Wp)
{
  int t = blockIdx.x * 256 + threadIdx.x;   // 0..49151
  int lane = t & 63;
  int rest = t >> 6;
  int s = rest % 48;
  int hc = rest / 48;
  int c2 = hc & 1, h = hc >> 1;
  int ml = lane & 15, sgk = lane >> 4;
  const float* W; int col, ks;
  if (s < 32) { int tl = s >> 3; ks = s & 7; W = c2 ? Wk : Wq; col = tl * 16 + ml; }
  else        { int tv = (s >> 3) - 4; ks = s & 7; W = Wv; col = c2 * 32 + tv * 16 + ml; }
  int k0 = ks * 32 + sgk * 8;
  u16 o[8];
#pragma unroll
  for (int j = 0; j < 8; j++)
    o[j] = f2bf(W[((size_t)h * 256 + k0 + j) * 64 + col]);
  ushort4* dst = (ushort4*)(Wp + (size_t)t * 8);
  dst[0] = make_ushort4(o[0], o[1], o[2], o[3]);
  dst[1] = make_ushort4(o[4], o[5], o[6], o[7]);
}

// ---------------------------------------------------------------------------
// kW: Wr[k][e] = (mean_h Wv)[k][:] @ Wm[:][e], packed WrP[e][k] bf16;
// br[e] = (mean_h bv) @ Wm + bm.  Residual is linear in x so v is never
// needed downstream.
// ---------------------------------------------------------------------------
__global__ __launch_bounds__(256) void kW(
    const float* __restrict__ Wv, const float* __restrict__ bv,
    const float* __restrict__ Wm, const float* __restrict__ bm,
    u16* __restrict__ WrP, float* __restrict__ br)
{
  __shared__ float wvb[4][64];
  int tid = threadIdx.x;
  int b = blockIdx.x;                 // k-rows 4b..4b+3
  {
    int kl = tid >> 6, d = tid & 63;
    float s = 0.f;
#pragma unroll
    for (int h = 0; h < NH; h++)
      s += Wv[((size_t)h * 256 + b * 4 + kl) * 64 + d];
    wvb[kl][d] = s * 0.125f;
  }
  __syncthreads();
  {
    int kl = tid >> 6, e = tid & 63;
    float acc = 0.f;
#pragma unroll
    for (int d = 0; d < 64; d++)
      acc += wvb[kl][d] * Wm[d * 64 + e];
    WrP[e * 256 + b * 4 + kl] = f2bf(acc);
  }
  if (b == 0 && tid < 64) {
    int e = tid;
    float s = 0.f;
    for (int d = 0; d < 64; d++) {
      float vb = 0.f;
#pragma unroll
      for (int h = 0; h < NH; h++) vb += bv[h * 64 + d];
      s += 0.125f * vb * Wm[d * 64 + e];
    }
    br[e] = s + bm[e];
  }
}

// ---------------------------------------------------------------------------
// k1: per-head persistent blocks (blockIdx = rc + 64*h). B-frags straight
// from global xb (no xs LDS). Computes q,k,v; writes only phi_q; phi_k and
// v are staged [feat][row] in LDS each subtile and consumed by in-block
// kTv MFMAs accumulating in AGPRs (k2 is merged in). Partials -> P.
// ---------------------------------------------------------------------------
__global__ __launch_bounds__(256, 2) void k1_gemm_phi(
    const u16* __restrict__ xb, const u16* __restrict__ Wp,
    const float* __restrict__ bq, const float* __restrict__ bk,
    const float* __restrict__ bv, const float* __restrict__ nsc,
    u16* __restrict__ phi_q, float* __restrict__ P)
{
  __shared__ u16 vws[2048 * 8];     // 32 KB v W-fragments
  __shared__ u16 pkT[64][36];       // phi_k [feat][row], 4.6 KB
  __shared__ u16 vT[64][36];        // v     [feat][row], 4.6 KB
  __shared__ u16 stq[2][16][72];    // wave-local q store staging, 4.6 KB
  __shared__ float biasl[192];

  const int tid = threadIdx.x;
  const int wv = tid >> 6, lane = tid & 63;
  const int c2 = wv & 1, rg = wv >> 1;
  const int m = lane & 15, sg = lane >> 4;
  const int rc = blockIdx.x & 63, h = blockIdx.x >> 6;
  const int n0 = rc * RPC;

  if (tid < 192) {
    const float* bp = tid < 64 ? bq : (tid < 128 ? bk : bv);
    biasl[tid] = bp[h * 64 + (tid & 63)];
  }

  // resident q(c2=0)/k(c2=1) W fragments: 128 VGPR
  const u16* wb = Wp + (size_t)(h * 2 + c2) * (48 * 64 * 8);
  s16x8 wq[4][8];
#pragma unroll
  for (int t = 0; t < 4; t++)
#pragma unroll
    for (int ks = 0; ks < 8; ks++)
      wq[t][ks] = *(const s16x8*)(wb + ((t * 8 + ks) * 64 + lane) * 8);

  // v W fragments -> LDS
#pragma unroll
  for (int i2 = 0; i2 < 8; i2++) {
    int u = tid + i2 * 256;
    int tl = u >> 9, ks = (u >> 6) & 7, ln = u & 63;
    const u16* src = Wp + ((size_t)(h * 2 + (tl >> 1)) * 48 + 32 + (tl & 1) * 8 + ks) * (64 * 8)
                     + (size_t)ln * 8;
    *(s16x8*)(vws + (size_t)u * 8) = *(const s16x8*)src;
  }
  __syncthreads();

  const float inv_denom = 1.0f / (fabsf(nsc[0]) + 1e-6f);
  const int rowl = rg * 16 + m;

  f32x4 kacc[4];
#pragma unroll
  for (int t = 0; t < 4; t++) kacc[t] = (f32x4){0.f, 0.f, 0.f, 0.f};
  f32x4 sacc = (f32x4){0.f, 0.f, 0.f, 0.f};
  s16x8 onesf;
#pragma unroll
  for (int j = 0; j < 8; j++) onesf[j] = (m == 0) ? (short)0x3F80 : (short)0;

  for (int s = 0; s < NSUB; s++) {
    int nrow = n0 + s * 32 + rowl;
    bool valid = nrow < NROWS;
    const u16* xrow = xb + (size_t)(valid ? nrow : NROWS - 1) * 256;

    f32x4 aq[4], av[2];
#pragma unroll
    for (int t = 0; t < 4; t++) aq[t] = (f32x4){0.f, 0.f, 0.f, 0.f};
    av[0] = (f32x4){0.f, 0.f, 0.f, 0.f};
    av[1] = (f32x4){0.f, 0.f, 0.f, 0.f};
#pragma unroll
    for (int ks = 0; ks < 8; ks++) {
      s16x8 bf = *(const s16x8*)(xrow + ks * 32 + sg * 8);
#pragma unroll
      for (int t = 0; t < 4; t++)
        aq[t] = __builtin_amdgcn_mfma_f32_16x16x32_bf16(wq[t][ks], bf, aq[t], 0, 0, 0);
      s16x8 vw0 = *(const s16x8*)(vws + (((c2 * 2 + 0) * 8 + ks) * 64 + lane) * 8);
      s16x8 vw1 = *(const s16x8*)(vws + (((c2 * 2 + 1) * 8 + ks) * 64 + lane) * 8);
      av[0] = __builtin_amdgcn_mfma_f32_16x16x32_bf16(vw0, bf, av[0], 0, 0, 0);
      av[1] = __builtin_amdgcn_mfma_f32_16x16x32_bf16(vw1, bf, av[1], 0, 0, 0);
    }

    // epilogue: bias + phi + in-wave norm (lane m = row, ch = t*16+sg*4+r)
    f32x4 bqk[4], bvv[2];
#pragma unroll
    for (int t = 0; t < 4; t++) bqk[t] = *(const f32x4*)&biasl[c2 * 64 + t * 16 + sg * 4];
#pragma unroll
    for (int tv = 0; tv < 2; tv++) bvv[tv] = *(const f32x4*)&biasl[128 + c2 * 32 + tv * 16 + sg * 4];

    float vq[4][4];
    float s2 = 0.f, s4 = 0.f;
#pragma unroll
    for (int t = 0; t < 4; t++)
#pragma unroll
      for (int r = 0; r < 4; r++) {
        float y = (fmaxf(aq[t][r] + bqk[t][r], 0.f) + 1e-6f) * inv_denom;
        float y2 = y * y;
        vq[t][r] = y2;
        s2 += y2; s4 += y2 * y2;
      }
    s2 += __shfl_xor(s2, 16); s2 += __shfl_xor(s2, 32);
    s4 += __shfl_xor(s4, 16); s4 += __shfl_xor(s4, 32);
    float sc = sqrtf(s2) / (sqrtf(s4) + 1e-12f);
    float scm = valid ? sc : 0.f;

    if (c2 == 0) {
      // phi_q: wave-local transpose staging + coalesced flush
      u16* sq = &stq[rg][0][0] + m * 72;
#pragma unroll
      for (int t = 0; t < 4; t++)
        *(ushort4*)(sq + ((t + m) & 3) * 16 + sg * 4) =
          make_ushort4(f2bf(vq[t][0] * sc), f2bf(vq[t][1] * sc),
                       f2bf(vq[t][2] * sc), f2bf(vq[t][3] * sc));
      int r_ = lane >> 2, tc = lane & 3;
      const u16* a = &stq[rg][0][0] + r_ * 72 + ((tc + r_) & 3) * 16;
      s16x8 p0 = *(const s16x8*)a;
      s16x8 p1 = *(const s16x8*)(a + 8);
      int n = n0 + s * 32 + rg * 16 + r_;
      if (n < NROWS) {
        u16* dst = phi_q + ((size_t)h * NROWS + n) * 64 + tc * 16;
        *(s16x8*)dst = p0;
        *(s16x8*)(dst + 8) = p1;
      }
    } else {
      // phi_k -> pkT [feat][row]
#pragma unroll
      for (int t = 0; t < 4; t++)
#pragma unroll
        for (int r = 0; r < 4; r++)
          pkT[t * 16 + sg * 4 + r][rowl] = f2bf(vq[t][r] * scm);
    }
    // v -> vT [feat][row] (each wave writes its channel half)
#pragma unroll
    for (int tv = 0; tv < 2; tv++)
#pragma unroll
      for (int r = 0; r < 4; r++) {
        float vval = valid ? (av[tv][r] + bvv[tv][r]) : 0.f;
        vT[c2 * 32 + tv * 16 + sg * 4 + r][rowl] = f2bf(vval);
      }
    __syncthreads();

    // in-block kTv: K=32 over this subtile's rows; wave owns m-tile wv
    {
      s16x8 afr = *(const s16x8*)&pkT[wv * 16 + m][sg * 8];
#pragma unroll
      for (int t = 0; t < 4; t++) {
        s16x8 bfr = *(const s16x8*)&vT[t * 16 + m][sg * 8];
        kacc[t] = __builtin_amdgcn_mfma_f32_16x16x32_bf16(afr, bfr, kacc[t], 0, 0, 0);
      }
      sacc = __builtin_amdgcn_mfma_f32_16x16x32_bf16(afr, onesf, sacc, 0, 0, 0);
    }
    __syncthreads();
  }

  // P partial: [d 0..63][mfeat] rows + row 64 = sumk
  float* pb = P + (size_t)blockIdx.x * 4160;
#pragma unroll
  for (int t = 0; t < 4; t++)
#pragma unroll
    for (int r = 0; r < 4; r++)
      pb[(t * 16 + m) * 64 + wv * 16 + sg * 4 + r] = kacc[t][r];
  if (m == 0)
#pragma unroll
    for (int r = 0; r < 4; r++)
      pb[4096 + wv * 16 + sg * 4 + r] = sacc[r];
}

// ---------------------------------------------------------------------------
// k25: reduce 64 chunk-partials per head -> bf16 kTvT[8][65][64]
// ---------------------------------------------------------------------------
__global__ __launch_bounds__(256) void k25_reduce(
    const float* __restrict__ P, u16* __restrict__ kTvT)
{
  int idx = blockIdx.x * 256 + threadIdx.x;
  if (idx >= NH * 4160) return;
  int h = idx / 4160, i = idx - h * 4160;
  float s = 0.f;
  for (int rcc = 0; rcc < NCH; rcc++)
    s += P[(size_t)(rcc + 64 * h) * 4160 + i];
  kTvT[idx] = f2bf(s);
}

// ---------------------------------------------------------------------------
// k3: out = mean_h( (phi_q@kTv[h]) / (phi_q.sum_k[h]+1e-6) ) + x@Wr + br;
// Lorentz lift. Zero LDS, zero barriers.
// ---------------------------------------------------------------------------
__global__ __launch_bounds__(256) void k3_out(
    const u16* __restrict__ phi_q, const u16* __restrict__ xb,
    const u16* __restrict__ kTvT, const u16* __restrict__ WrP,
    const float* __restrict__ br, float* __restrict__ out)
{
  const int tid = threadIdx.x;
  const int wv = tid >> 6, lane = tid & 63;
  const int m = lane & 15, sg = lane >> 4;
  const int n0 = blockIdx.x * 64;
  const int rw = wv * 16;
  const int n = n0 + rw + m;
  const int nc = n < NROWS ? n : NROWS - 1;

  float brv[4];
#pragma unroll
  for (int t = 0; t < 4; t++) brv[t] = br[t * 16 + m];

  f32x4 zero4 = {0.f, 0.f, 0.f, 0.f};
  s16x8 zero8 = {0, 0, 0, 0, 0, 0, 0, 0};
  f32x4 osum[4];
#pragma unroll
  for (int t = 0; t < 4; t++) osum[t] = zero4;

  for (int h = 0; h < NH; h++) {
    const u16* pqb = phi_q + ((size_t)h * NROWS + nc) * 64;
    const u16* kb = kTvT + h * 4160;
    f32x4 accn[4];
#pragma unroll
    for (int t = 0; t < 4; t++) accn[t] = zero4;
    f32x4 accd = zero4;
#pragma unroll
    for (int ks = 0; ks < 2; ks++) {
      s16x8 aq = *(const s16x8*)(pqb + ks * 32 + sg * 8);
#pragma unroll
      for (int t = 0; t < 4; t++) {
        s16x8 bfv = *(const s16x8*)(kb + (size_t)(t * 16 + m) * 64 + ks * 32 + sg * 8);
        accn[t] = __builtin_amdgcn_mfma_f32_16x16x32_bf16(aq, bfv, accn[t], 0, 0, 0);
      }
      s16x8 bd = zero8;
      if (m == 0)
        bd = *(const s16x8*)(kb + 4096 + ks * 32 + sg * 8);
      accd = __builtin_amdgcn_mfma_f32_16x16x32_bf16(aq, bd, accd, 0, 0, 0);
    }
#pragma unroll
    for (int r = 0; r < 4; r++) {
      float den = __shfl(accd[r], lane & 48);
      float rinv = 1.0f / (den + 1e-6f);
#pragma unroll
      for (int t = 0; t < 4; t++) osum[t][r] += accn[t][r] * rinv;
    }
  }

  // residual x @ Wr (K=256)
  f32x4 accr[4];
#pragma unroll
  for (int t = 0; t < 4; t++) accr[t] = zero4;
  const u16* xrow = xb + (size_t)nc * 256;
#pragma unroll
  for (int ks = 0; ks < 8; ks++) {
    s16x8 ax = *(const s16x8*)(xrow + ks * 32 + sg * 8);
#pragma unroll
    for (int t = 0; t < 4; t++) {
      s16x8 bw = *(const s16x8*)(WrP + (size_t)(t * 16 + m) * 256 + ks * 32 + sg * 8);
      accr[t] = __builtin_amdgcn_mfma_f32_16x16x32_bf16(ax, bw, accr[t], 0, 0, 0);
    }
  }

#pragma unroll
  for (int r = 0; r < 4; r++) {
    int nn = n0 + rw + sg * 4 + r;
    float v4[4];
    float ssq = 0.f;
#pragma unroll
    for (int t = 0; t < 4; t++) {
      float o = osum[t][r] * 0.125f + accr[t][r] + brv[t];
      v4[t] = o;
      ssq += o * o;
    }
    ssq += __shfl_xor(ssq, 1);
    ssq += __shfl_xor(ssq, 2);
    ssq += __shfl_xor(ssq, 4);
    ssq += __shfl_xor(ssq, 8);
    if (nn < NROWS) {
      if (m == 0) out[(size_t)nn * 65] = sqrtf(ssq + 1.0f);
#pragma unroll
      for (int t = 0; t < 4; t++)
        out[(size_t)nn * 65 + 1 + t * 16 + m] = v4[t];
    }
  }
}

// ---------------------------------------------------------------------------
extern "C" void kernel_launch(void* const* d_in, const int* in_sizes, int n_in,
                              void* d_out, int out_size, void* d_ws, size_t ws_size,
                              hipStream_t stream) {
  const float* x   = (const float*)d_in[0];
  const float* Wq  = (const float*)d_in[1];
  const float* bq  = (const float*)d_in[2];
  const float* Wk  = (const float*)d_in[3];
  const float* bk  = (const float*)d_in[4];
  const float* Wv  = (const float*)d_in[5];
  const float* bv  = (const float*)d_in[6];
  const float* nsc = (const float*)d_in[7];
  const float* Wm  = (const float*)d_in[8];
  const float* bm  = (const float*)d_in[9];
  float* out = (float*)d_out;

  char* ws = (char*)d_ws;
  u16* xb    = (u16*)(ws);                                 // 51,200,000 B
  u16* phi_q = (u16*)(ws + 51200000);                      // 102,400,000 B
  u16* Wp    = (u16*)(ws + 153600000);                     // 786,432 B
  float* P   = (float*)(ws + 154386432);                   // 512*4160*4 = 8,519,680 B
  u16* kTvT  = (u16*)(ws + 162906112);                     // 66,560 B
  u16* WrP   = (u16*)(ws + 162972672);                     // 32,768 B
  float* br  = (float*)(ws + 163005440);                   // 256 B

  k_cvt<<<12500, 256, 0, stream>>>(x, xb);
  k0_pack<<<192, 256, 0, stream>>>(Wq, Wk, Wv, Wp);
  kW<<<64, 256, 0, stream>>>(Wv, bv, Wm, bm, WrP, br);
  k1_gemm_phi<<<512, 256, 0, stream>>>(xb, Wp, bq, bk, bv, nsc, phi_q, P);
  k25_reduce<<<130, 256, 0, stream>>>(P, kTvT);
  k3_out<<<1563, 256, 0, stream>>>(phi_q, xb, kTvT, WrP, br, out);
}